// Round 11
// baseline (304.815 us; speedup 1.0000x reference)
//
#include <hip/hip_runtime.h>

// DispNetC correlation volume: out[b,d,h,w] = mean_c L[b,c,h,w]*R[b,c,h,w-d]
// for w>=d, else 0.  f32 in / f32 out.
//
// R10 post-mortem: time invariant (~50us) to staging style AND to warm/cold
// LLC -> not BW/latency-chain bound; the binding variable is load-issue duty
// cycle (8-16 lockstepped waves/CU). This version: C split over 4 slices ->
// 2048 small blocks (5 resident/CU, 20 waves/CU), staging = ~whole block
// lifetime, one barrier pair, no lockstep loop. Partials combined via f32
// atomicAdd into hipMemsetAsync-zeroed d_out (also kills the triangle fill).
// Staging swizzle + band-MFMA + epilogue plumbing = R6/R7 hardware-verified.

typedef __attribute__((ext_vector_type(8))) short short8;   // MFMA A/B frag
typedef __attribute__((ext_vector_type(4))) float floatx4;  // MFMA C/D frag

#define NB 8
#define NC 256
#define NH 64
#define NWD 128
#define ND 40
#define KC 64   // channels per block (c-slice)

__global__ __launch_bounds__(256) void corr_split(
    const float* __restrict__ Lg,
    const float* __restrict__ Rg,
    float* __restrict__ out)
{
  __shared__ __align__(16) unsigned short Ls[NWD * KC];  // 16 KB
  __shared__ __align__(16) unsigned short Rs[NWD * KC];  // 16 KB

  const int blk  = blockIdx.x;
  const int s    = blk >> 9;        // c-slice 0..3
  const int rem  = blk & 511;
  const int b    = rem >> 6;        // NH = 64
  const int h    = rem & 63;
  const int tid  = threadIdx.x;
  const int lane = tid & 63;
  const int wave = tid >> 6;
  const int m    = lane & 15;
  const int q    = lane >> 4;

  const int ws = tid & 127;        // lane -> w for staging (coalesced 256B/instr)
  const int ch = tid >> 7;         // which 8-c slot within each 16-c group
  const size_t HW   = (size_t)NH * NWD;
  const size_t goff = (size_t)b * NC * HW + (size_t)h * NWD
                    + (size_t)(s * KC) * HW + ws;

  // ---- stage this block's 64 channels: f32 load, round-half-up bf16, pack ----
  // [w][c] layout, XOR-swizzled 8-c groups (R6-verified: 0 bank conflicts).
  #pragma unroll
  for (int it = 0; it < 4; ++it) {
    const size_t g = goff + (size_t)(it * 16 + ch * 8) * HW;
    unsigned int lv[4], rv[4];
    #pragma unroll
    for (int p = 0; p < 4; ++p) {
      const unsigned int a0 = __float_as_uint(Lg[g + (size_t)(2 * p) * HW]) + 0x8000u;
      const unsigned int a1 = __float_as_uint(Lg[g + (size_t)(2 * p + 1) * HW]) + 0x8000u;
      lv[p] = (a0 >> 16) | (a1 & 0xFFFF0000u);
      const unsigned int b0 = __float_as_uint(Rg[g + (size_t)(2 * p) * HW]) + 0x8000u;
      const unsigned int b1 = __float_as_uint(Rg[g + (size_t)(2 * p + 1) * HW]) + 0x8000u;
      rv[p] = (b0 >> 16) | (b1 & 0xFFFF0000u);
    }
    const int grp = it * 2 + ch;                        // 8-c group, 0..7
    const int pos = ws * KC + ((grp ^ (ws & 7)) << 3);  // XOR swizzle
    *(uint4*)(&Ls[pos]) = make_uint4(lv[0], lv[1], lv[2], lv[3]);
    *(uint4*)(&Rs[pos]) = make_uint4(rv[0], rv[1], rv[2], rv[3]);
  }
  __syncthreads();

  // ---- band tiles (i, j=i+k), k=0..3; 26 tiles round-robined over 4 waves ----
  floatx4 acc[7];
  #pragma unroll
  for (int t = 0; t < 7; ++t) acc[t] = (floatx4){0.f, 0.f, 0.f, 0.f};
  #pragma unroll
  for (int ks = 0; ks < 2; ++ks) {       // two K=32 steps over the 64 channels
    #pragma unroll
    for (int tile = 0; tile < 26; ++tile) {
      if ((tile & 3) != wave) continue;
      const int i  = (tile < 8) ? tile : (tile < 15) ? tile - 8
                   : (tile < 21) ? tile - 15 : tile - 21;
      const int k  = (tile < 8) ? 0 : (tile < 15) ? 1 : (tile < 21) ? 2 : 3;
      const int j  = i + k;
      const int tt = tile >> 2;
      const int ra = 16 * i + m;         // w' row for A (from R)
      const int rb = 16 * j + m;         // w  col for B (from L)
      const int grp = ks * 4 + q;        // lane reads c = 32*ks + 8*q + [0..7]
      const short8 av = *(const short8*)(&Rs[ra * KC + ((grp ^ (ra & 7)) << 3)]);
      const short8 bv = *(const short8*)(&Ls[rb * KC + ((grp ^ (rb & 7)) << 3)]);
      acc[tt] = __builtin_amdgcn_mfma_f32_16x16x32_bf16(av, bv, acc[tt], 0, 0, 0);
    }
  }

  // ---- epilogue: scaled partial -> atomicAdd into pre-zeroed d_out ----
  // D layout: col = lane&15 (w within tile j), row = q*4+r (w' within tile i).
  #pragma unroll
  for (int tile = 0; tile < 26; ++tile) {
    if ((tile & 3) != wave) continue;
    const int i  = (tile < 8) ? tile : (tile < 15) ? tile - 8
                 : (tile < 21) ? tile - 15 : tile - 21;
    const int k  = (tile < 8) ? 0 : (tile < 15) ? 1 : (tile < 21) ? 2 : 3;
    const int j  = i + k;
    const int tt = tile >> 2;
    const int w  = 16 * j + m;
    #pragma unroll
    for (int r = 0; r < 4; ++r) {
      const int wp = 16 * i + q * 4 + r;
      const int d  = w - wp;
      if (d >= 0 && d < ND)
        atomicAdd(&out[(((size_t)b * ND + d) * NH + h) * NWD + w],
                  acc[tt][r] * 0.00390625f);  // * 1/256 per-slice partial
    }
  }
}

extern "C" void kernel_launch(void* const* d_in, const int* in_sizes, int n_in,
                              void* d_out, int out_size, void* d_ws, size_t ws_size,
                              hipStream_t stream) {
  // Zero d_out (harness poisons it 0xAA); w<d triangle stays zero, band is
  // accumulated atomically by the 4 c-slice blocks.
  hipMemsetAsync(d_out, 0, (size_t)out_size * sizeof(float), stream);
  corr_split<<<dim3(2048), dim3(256), 0, stream>>>(
      (const float*)d_in[0], (const float*)d_in[1], (float*)d_out);
}

// Round 12
// 150.513 us; speedup vs baseline: 2.0252x; 2.0252x over previous
//
#include <hip/hip_runtime.h>

// DispNetC correlation volume: out[b,d,h,w] = mean_c L[b,c,h,w]*R[b,c,h,w-d]
// for w>=d, else 0.  f32 in / f32 out.
//
// R6-R10 pinned at ~50us (2.7 TB/s delivery) across all staging schemes,
// warm or cold LLC. Invariant: per-(b,h) blocks read 512B segments on a
// 32KB stride -> 2 sectors/instr, L2/LLC bin-camping. This version: block
// owns an h-PAIR -> float4 loads are 1KB CONTIGUOUS (8 sectors/instr, 4x
// bin spread), 256 blocks (one tail-free round), 16 waves/CU. Lane-holds-4w
// data is transposed to the MFMA [w][c] layout via per-wave-private LDS
// scratch. Compute = R6's hardware-verified 26-tile band MFMA, x2 h.

typedef __attribute__((ext_vector_type(8))) short short8;   // MFMA A/B frag
typedef __attribute__((ext_vector_type(4))) float floatx4;  // MFMA C/D frag

#define NB 8
#define NC 256
#define NH 64
#define NWD 128
#define ND 40
#define KC 64          // channels per chunk; 4 chunks
// s_waitcnt imm: vm[3:0] | exp[6:4]=7 | lgkm[11:8] | vm[5:4]@[15:14]
#define WCNT(vm, lgkm) (((vm) & 15) | (((vm) >> 4) << 14) | (7 << 4) | ((lgkm) << 8))

// LDS map (bytes):
//   Lbuf [hh][w][KC] u16 swizzled : 0      (32 KB)
//   Rbuf same                     : 32768  (32 KB)
//   scratch, per-wave 8*132 f32   : 65536 + wv*4224  (67.6 KB)
// total 133120 B -> 1 block/CU, 16 waves.

__global__ __launch_bounds__(1024, 4) void corr_hpair(
    const float* __restrict__ Lg,
    const float* __restrict__ Rg,
    float* __restrict__ out)
{
  __shared__ __align__(16) unsigned char smem[65536 + 16 * 4224];

  const int blk  = blockIdx.x;
  const int b    = blk >> 5;       // 8 b
  const int h2   = blk & 31;       // h-pair index; h = 2*h2 + hh
  const int tid  = threadIdx.x;
  const int lane = tid & 63;
  const int wv   = tid >> 6;       // 0..15
  const int m    = lane & 15;
  const int q    = lane >> 4;

  const size_t HW    = (size_t)NH * NWD;
  const size_t gbase = (size_t)b * NC * HW + (size_t)(h2 * 2) * NWD;

  float* scr = (float*)(smem + 65536 + wv * 4224);   // [8][132] f32

  floatx4 acc[4];
  #pragma unroll
  for (int i = 0; i < 4; ++i) acc[i] = (floatx4){0.f, 0.f, 0.f, 0.f};

  for (int chunk = 0; chunk < 4; ++chunk) {
    __syncthreads();  // prev MFMA frag reads done before finals overwrite

    // ---- stage: 2 units/wave; unit = one array x 4 channels x both h ----
    #pragma unroll
    for (int uu = 0; uu < 2; ++uu) {
      const int ug  = wv * 2 + uu;     // 0..31
      const int arr = ug & 1;          // 0 = L, 1 = R
      const int cq  = ug >> 1;         // c-quad 0..15
      const int c0  = chunk * KC + cq * 4;
      const int gu  = cq >> 1;         // 8-c group 0..7
      const int su  = cq & 1;          // which b64 half of the group
      const float* src = arr ? Rg : Lg;

      // 4 contiguous-1KB loads: rows (c0+i, h0) and (c0+i, h1)
      float4 v[4];
      #pragma unroll
      for (int i = 0; i < 4; ++i) {
        const float* gp = src + gbase + (size_t)(c0 + i) * HW
                        + (lane >> 5) * NWD + 4 * (lane & 31);
        v[i] = *(const float4*)gp;
      }
      // scratch write: row = 2*c' + hh, padded stride 132 (2-way free)
      #pragma unroll
      for (int i = 0; i < 4; ++i)
        *(float4*)(scr + (2 * i + (lane >> 5)) * 132 + 4 * (lane & 31)) = v[i];
      __builtin_amdgcn_s_waitcnt(WCNT(63, 0));  // scratch visible to own wave

      // gather 4 c per (hh,w), pack bf16 (round-half-up), b64 to final
      unsigned short* fin = (unsigned short*)(smem + arr * 32768);
      #pragma unroll
      for (int t = 0; t < 4; ++t) {
        const int hh = t >> 1;
        const int w  = lane + (t & 1) * 64;
        float f[4];
        #pragma unroll
        for (int c1 = 0; c1 < 4; ++c1)
          f[c1] = scr[(2 * c1 + hh) * 132 + w];
        const unsigned int lo =
            ((__float_as_uint(f[0]) + 0x8000u) >> 16) |
            ((__float_as_uint(f[1]) + 0x8000u) & 0xFFFF0000u);
        const unsigned int hi =
            ((__float_as_uint(f[2]) + 0x8000u) >> 16) |
            ((__float_as_uint(f[3]) + 0x8000u) & 0xFFFF0000u);
        // u16 index: hh*8192 + w*64 + ((gu ^ (w&7))<<3) + 4*su  (swizzled)
        *(uint2*)(fin + hh * 8192 + w * 64 + ((gu ^ (w & 7)) << 3) + 4 * su) =
            make_uint2(lo, hi);
      }
      __builtin_amdgcn_s_waitcnt(WCNT(63, 0));  // gathers done before scratch reuse
    }
    __syncthreads();

    // ---- MFMA: 52 instances (2h x 26 band tiles) over 16 waves ----
    const unsigned short* Lb = (const unsigned short*)smem;
    const unsigned short* Rb = (const unsigned short*)(smem + 32768);
    #pragma unroll
    for (int ks2 = 0; ks2 < 2; ++ks2) {        // two K=32 steps per chunk
      #pragma unroll
      for (int li = 0; li < 4; ++li) {
        const int inst = wv + (li << 4);
        if (inst >= 52) break;
        const int hh   = (inst >= 26) ? 1 : 0;
        const int tile = inst - hh * 26;
        const int i  = (tile < 8) ? tile : (tile < 15) ? tile - 8
                     : (tile < 21) ? tile - 15 : tile - 21;
        const int k  = (tile < 8) ? 0 : (tile < 15) ? 1 : (tile < 21) ? 2 : 3;
        const int j  = i + k;
        const int g  = ks2 * 4 + q;            // c = 32*ks2 + 8*q + e
        const int ra = 16 * i + m;             // w' row for A (from R)
        const int rb = 16 * j + m;             // w  col for B (from L)
        const short8 av =
            *(const short8*)(Rb + hh * 8192 + ra * 64 + ((g ^ (ra & 7)) << 3));
        const short8 bv =
            *(const short8*)(Lb + hh * 8192 + rb * 64 + ((g ^ (rb & 7)) << 3));
        acc[li] = __builtin_amdgcn_mfma_f32_16x16x32_bf16(av, bv, acc[li], 0, 0, 0);
      }
    }
  }

  // ---- epilogue: D layout col=lane&15 (w in tile j), row=q*4+r (w' in tile i) ----
  #pragma unroll
  for (int li = 0; li < 4; ++li) {
    const int inst = wv + (li << 4);
    if (inst >= 52) break;
    const int hh   = (inst >= 26) ? 1 : 0;
    const int tile = inst - hh * 26;
    const int i  = (tile < 8) ? tile : (tile < 15) ? tile - 8
                 : (tile < 21) ? tile - 15 : tile - 21;
    const int k  = (tile < 8) ? 0 : (tile < 15) ? 1 : (tile < 21) ? 2 : 3;
    const int j  = i + k;
    const int h  = h2 * 2 + hh;
    const int w  = 16 * j + m;
    #pragma unroll
    for (int r = 0; r < 4; ++r) {
      const int wp = 16 * i + q * 4 + r;
      const int d  = w - wp;
      if (d >= 0 && d < ND)
        out[(((size_t)b * ND + d) * NH + h) * NWD + w] = acc[li][r] * 0.00390625f;
    }
  }

  // ---- zero-fill the w<d triangle for both h (d_out poisoned each launch) ----
  for (int t = tid; t < 2 * ND * ND; t += 1024) {
    const int hh = (t >= ND * ND) ? 1 : 0;
    const int tt = t - hh * ND * ND;
    const int d  = tt / ND;
    const int w  = tt - d * ND;
    if (w < d)
      out[(((size_t)b * ND + d) * NH + (h2 * 2 + hh)) * NWD + w] = 0.0f;
  }
}

extern "C" void kernel_launch(void* const* d_in, const int* in_sizes, int n_in,
                              void* d_out, int out_size, void* d_ws, size_t ws_size,
                              hipStream_t stream) {
  corr_hpair<<<dim3(256), dim3(1024), 0, stream>>>(
      (const float*)d_in[0], (const float*)d_in[1], (float*)d_out);
}